// Round 5
// baseline (241.647 us; speedup 1.0000x reference)
//
#include <hip/hip_runtime.h>

// Problem constants (from setup_inputs): q,k are (4,4,4096,256) float32; h=w=64 at runtime.
constexpr int B_ = 4, H_ = 4, N_ = 4096, C_ = 256;
constexpr long long TENS = (long long)B_ * H_ * N_ * C_;   // 16,777,216 elements per tensor
constexpr int BH = B_ * H_;                                // 16 slabs
constexpr int F4_PER_POS = C_ / 4;                         // 64 float4 per position
constexpr unsigned SLAB_F4 = (unsigned)(N_ * F4_PER_POS);  // 262,144 float4 per bh slab

// Each thread owns one (pos, channel-quad) and 4 of the 16 bh slabs.
// 2^20 threads -> 4096 workgroups; trig amortized 4x.
constexpr int SLABS_PER_THREAD = 4;
constexpr int GROUPS = BH / SLABS_PER_THREAD;              // 4
constexpr unsigned NTHREADS = SLAB_F4 * GROUPS;            // 1,048,576
constexpr unsigned NBLOCKS = NTHREADS / 256;               // 4096

typedef float f32x4 __attribute__((ext_vector_type(4)));

__device__ __forceinline__ unsigned read_w(const int* __restrict__ wp) {
    // Robust read of scalar w: accept int32 (expected) or float32 bit patterns.
    // readfirstlane forces the value into an SGPR (wave-uniform broadcast).
    int wi = __builtin_amdgcn_readfirstlane(wp[0]);
    if (wi <= 0 || wi > 65536) {
        float wf = __int_as_float(wi);
        wi = (wf > 0.0f && wf <= 65536.0f) ? (int)wf : 64;
    }
    return (unsigned)wi;
}

// ---------------------------------------------------------------------------
// Fused RoPE-2D, round 5 (resubmit of round 4 — infra failure, never ran):
// identical structure to round 3 but with ALL nontemporal hints removed
// (plain cached loads/stores — the m13 copy probe that achieves 6.29 TB/s
// uses plain float4 accesses; NT is the only factor common to all three
// prior ~3.8 TB/s variants).
//   flat index within a slab: idx = pos*64 + fq, slab stride 2^18 float4s.
// ---------------------------------------------------------------------------
__global__ __launch_bounds__(256, 8) void rope2d_plain_kernel(
    const f32x4* __restrict__ q4,
    const f32x4* __restrict__ k4,
    const int* __restrict__ wp,
    f32x4* __restrict__ oq4,
    f32x4* __restrict__ ok4)
{
    const unsigned tid = blockIdx.x * 256 + threadIdx.x;    // [0, 2^20)
    const unsigned idx = tid & (SLAB_F4 - 1);               // (pos, fq) quad index
    const unsigned bh0 = (tid >> 18) * SLABS_PER_THREAD;    // first slab of this thread

    const unsigned w = read_w(wp);
    const unsigned pos = idx >> 6;                          // sequence index 0..4095
    const unsigned fq  = idx & 63;                          // float4 index within channel row
    const unsigned x = pos % w;
    const unsigned y = pos / w;

    // channel quad fq covers pairs j0=2*fq, j0+1. j0<64 (fq<32) => x-side, else y-side.
    const float mult = (fq < 32) ? (float)x : (float)y;
    const int f0 = (int)(2u * (fq & 31u));                  // even frequency index in [0,64)

    // base[f] = 10000^(-f/64) = exp2(f * -log2(10000)/64)
    constexpr float NEG_LOG2_THETA_OVER_64 = -0.20762050593045494f;
    float c0, s0, c1, s1;
    sincosf(mult * exp2f((float)f0       * NEG_LOG2_THETA_OVER_64), &s0, &c0);
    sincosf(mult * exp2f((float)(f0 + 1) * NEG_LOG2_THETA_OVER_64), &s1, &c1);

    // Apply to 4 bh slabs: 2 loads + 8 FMA + 2 stores per slab, plain cached path.
    #pragma unroll
    for (int i = 0; i < SLABS_PER_THREAD; ++i) {
        const unsigned t = (bh0 + (unsigned)i) * SLAB_F4 + idx;
        const f32x4 qa = q4[t];
        const f32x4 ka = k4[t];

        f32x4 r;
        r.x = fmaf(c0, qa.x, -s0 * qa.y);
        r.y = fmaf(s0, qa.x,  c0 * qa.y);
        r.z = fmaf(c1, qa.z, -s1 * qa.w);
        r.w = fmaf(s1, qa.z,  c1 * qa.w);
        oq4[t] = r;

        r.x = fmaf(c0, ka.x, -s0 * ka.y);
        r.y = fmaf(s0, ka.x,  c0 * ka.y);
        r.z = fmaf(c1, ka.z, -s1 * ka.w);
        r.w = fmaf(s1, ka.z,  c1 * ka.w);
        ok4[t] = r;
    }
}

extern "C" void kernel_launch(void* const* d_in, const int* in_sizes, int n_in,
                              void* d_out, int out_size, void* d_ws, size_t ws_size,
                              hipStream_t stream) {
    // dict order: q, k, h, w  (h,w are 1-element arrays on device)
    const int* wp = (const int*)d_in[3];
    float* out = (float*)d_out;                 // q_out flat, then k_out flat

    rope2d_plain_kernel<<<dim3(NBLOCKS), 256, 0, stream>>>(
        (const f32x4*)d_in[0], (const f32x4*)d_in[1], wp,
        (f32x4*)out, (f32x4*)(out + TENS));
}

// Round 6
// 238.274 us; speedup vs baseline: 1.0142x; 1.0142x over previous
//
#include <hip/hip_runtime.h>

// Problem constants (from setup_inputs): q,k are (4,4,4096,256) float32; h=w=64 at runtime.
constexpr int B_ = 4, H_ = 4, N_ = 4096, C_ = 256;
constexpr long long TENS = (long long)B_ * H_ * N_ * C_;   // 16,777,216 elements per tensor
constexpr int BH = B_ * H_;                                // 16 slabs
constexpr int F4_PER_POS = C_ / 4;                         // 64 float4 per position
constexpr unsigned SLAB_F4 = (unsigned)(N_ * F4_PER_POS);  // 262,144 float4 per bh slab

// Each thread owns one (pos, channel-quad) and 4 of the 16 bh slabs.
// 2^20 threads -> 4096 workgroups; trig amortized 4x.
constexpr int SLABS_PER_THREAD = 4;
constexpr int GROUPS = BH / SLABS_PER_THREAD;              // 4
constexpr unsigned NTHREADS = SLAB_F4 * GROUPS;            // 1,048,576
constexpr unsigned NBLOCKS = NTHREADS / 256;               // 4096

typedef float f32x4 __attribute__((ext_vector_type(4)));

__device__ __forceinline__ unsigned read_w(const int* __restrict__ wp) {
    // Robust read of scalar w: accept int32 (expected) or float32 bit patterns.
    int wi = __builtin_amdgcn_readfirstlane(wp[0]);
    if (wi <= 0 || wi > 65536) {
        float wf = __int_as_float(wi);
        wi = (wf > 0.0f && wf <= 65536.0f) ? (int)wf : 64;
    }
    return (unsigned)wi;
}

// ---------------------------------------------------------------------------
// Fused RoPE-2D, round 6: MIXED cache policy — single-variable A/B vs round 5.
//   * loads:  PLAIN (cached). q+k = 128 MB fit in the 256 MiB Infinity Cache;
//     round-5 counters showed FETCH=64MB<128MB, i.e. L3 was already serving
//     half the reads. NT loads (rounds 1-3) bypassed that and paid full HBM.
//   * stores: NONTEMPORAL. Round-5 plain stores ran at only 2.45 TB/s HBM-side
//     (write-allocate path + evicting q/k from L3); the 6.8 TB/s fill kernels
//     stream writes. NT stores also stop outputs evicting the resident inputs.
// Everything else identical to round 5.
// ---------------------------------------------------------------------------
__global__ __launch_bounds__(256, 8) void rope2d_mixed_kernel(
    const f32x4* __restrict__ q4,
    const f32x4* __restrict__ k4,
    const int* __restrict__ wp,
    f32x4* __restrict__ oq4,
    f32x4* __restrict__ ok4)
{
    const unsigned tid = blockIdx.x * 256 + threadIdx.x;    // [0, 2^20)
    const unsigned idx = tid & (SLAB_F4 - 1);               // (pos, fq) quad index
    const unsigned bh0 = (tid >> 18) * SLABS_PER_THREAD;    // first slab of this thread

    const unsigned w = read_w(wp);
    const unsigned pos = idx >> 6;                          // sequence index 0..4095
    const unsigned fq  = idx & 63;                          // float4 index within channel row
    const unsigned x = pos % w;
    const unsigned y = pos / w;

    // channel quad fq covers pairs j0=2*fq, j0+1. j0<64 (fq<32) => x-side, else y-side.
    const float mult = (fq < 32) ? (float)x : (float)y;
    const int f0 = (int)(2u * (fq & 31u));                  // even frequency index in [0,64)

    // base[f] = 10000^(-f/64) = exp2(f * -log2(10000)/64)
    constexpr float NEG_LOG2_THETA_OVER_64 = -0.20762050593045494f;
    float c0, s0, c1, s1;
    sincosf(mult * exp2f((float)f0       * NEG_LOG2_THETA_OVER_64), &s0, &c0);
    sincosf(mult * exp2f((float)(f0 + 1) * NEG_LOG2_THETA_OVER_64), &s1, &c1);

    // Apply to 4 bh slabs: 2 cached loads + 8 FMA + 2 NT stores per slab.
    #pragma unroll
    for (int i = 0; i < SLABS_PER_THREAD; ++i) {
        const unsigned t = (bh0 + (unsigned)i) * SLAB_F4 + idx;
        const f32x4 qa = q4[t];
        const f32x4 ka = k4[t];

        f32x4 r;
        r.x = fmaf(c0, qa.x, -s0 * qa.y);
        r.y = fmaf(s0, qa.x,  c0 * qa.y);
        r.z = fmaf(c1, qa.z, -s1 * qa.w);
        r.w = fmaf(s1, qa.z,  c1 * qa.w);
        __builtin_nontemporal_store(r, &oq4[t]);

        r.x = fmaf(c0, ka.x, -s0 * ka.y);
        r.y = fmaf(s0, ka.x,  c0 * ka.y);
        r.z = fmaf(c1, ka.z, -s1 * ka.w);
        r.w = fmaf(s1, ka.z,  c1 * ka.w);
        __builtin_nontemporal_store(r, &ok4[t]);
    }
}

extern "C" void kernel_launch(void* const* d_in, const int* in_sizes, int n_in,
                              void* d_out, int out_size, void* d_ws, size_t ws_size,
                              hipStream_t stream) {
    // dict order: q, k, h, w  (h,w are 1-element arrays on device)
    const int* wp = (const int*)d_in[3];
    float* out = (float*)d_out;                 // q_out flat, then k_out flat

    rope2d_mixed_kernel<<<dim3(NBLOCKS), 256, 0, stream>>>(
        (const f32x4*)d_in[0], (const f32x4*)d_in[1], wp,
        (f32x4*)out, (f32x4*)(out + TENS));
}

// Round 7
// 229.162 us; speedup vs baseline: 1.0545x; 1.0398x over previous
//
#include <hip/hip_runtime.h>

// Problem constants (from setup_inputs): q,k are (4,4,4096,256) float32; h=w=64 at runtime.
constexpr int B_ = 4, H_ = 4, N_ = 4096, C_ = 256;
constexpr long long TENS = (long long)B_ * H_ * N_ * C_;   // 16,777,216 elements per tensor
constexpr int BH = B_ * H_;                                // 16 slabs
constexpr int F4_PER_POS = C_ / 4;                         // 64 float4 per position
constexpr unsigned SLAB_F4 = (unsigned)(N_ * F4_PER_POS);  // 262,144 float4 per bh slab

// Each thread owns one (pos, channel-quad) and 4 of the 16 bh slabs.
constexpr int SLABS_PER_THREAD = 4;
constexpr int GROUPS = BH / SLABS_PER_THREAD;              // 4
constexpr unsigned NTHREADS = SLAB_F4 * GROUPS;            // 1,048,576
constexpr unsigned NBLOCKS = NTHREADS / 256;               // 4096

typedef float f32x4 __attribute__((ext_vector_type(4)));

__device__ __forceinline__ unsigned read_w(const int* __restrict__ wp) {
    // Robust read of scalar w: accept int32 (expected) or float32 bit patterns.
    int wi = __builtin_amdgcn_readfirstlane(wp[0]);
    if (wi <= 0 || wi > 65536) {
        float wf = __int_as_float(wi);
        wi = (wf > 0.0f && wf <= 65536.0f) ? (int)wf : 64;
    }
    return (unsigned)wi;
}

// ---------------------------------------------------------------------------
// Round 7: NT loads + NT stores (best measured cache policy, r2/r3) with a
// LOAD-BATCHED body: all 8 q/k loads issued into registers before any
// compute/store (explicit two-phase, full unroll -> static indices, ~56 VGPR).
// Rationale: fill kernels hit 6.65 TB/s at 9.5% occupancy -> streaming BW
// comes from per-wave MLP. r5/r6's interleaved body kept only ~2 loads in
// flight (VGPR=32); this keeps 8.
// ---------------------------------------------------------------------------
__global__ __launch_bounds__(256, 8) void rope2d_batch_kernel(
    const f32x4* __restrict__ q4,
    const f32x4* __restrict__ k4,
    const int* __restrict__ wp,
    f32x4* __restrict__ oq4,
    f32x4* __restrict__ ok4)
{
    const unsigned tid = blockIdx.x * 256 + threadIdx.x;    // [0, 2^20)
    const unsigned idx = tid & (SLAB_F4 - 1);               // (pos, fq) quad index
    const unsigned bh0 = (tid >> 18) * SLABS_PER_THREAD;    // first slab of this thread
    const unsigned base = bh0 * SLAB_F4 + idx;

    // ---- Phase 1: issue ALL payload loads (8 x nt global_load_dwordx4) ----
    f32x4 qa[SLABS_PER_THREAD], ka[SLABS_PER_THREAD];
    #pragma unroll
    for (int i = 0; i < SLABS_PER_THREAD; ++i) {
        const unsigned t = base + (unsigned)i * SLAB_F4;
        qa[i] = __builtin_nontemporal_load(&q4[t]);
        ka[i] = __builtin_nontemporal_load(&k4[t]);
    }

    // ---- Trig (overlaps load latency; amortized over 4 slabs) ----
    const unsigned w = read_w(wp);
    const unsigned pos = idx >> 6;                          // sequence index 0..4095
    const unsigned fq  = idx & 63;                          // float4 index within channel row
    const unsigned x = pos % w;
    const unsigned y = pos / w;
    // channel quad fq covers pairs j0=2*fq, j0+1. j0<64 (fq<32) => x-side, else y-side.
    const float mult = (fq < 32) ? (float)x : (float)y;
    const int f0 = (int)(2u * (fq & 31u));                  // even frequency index in [0,64)
    // base[f] = 10000^(-f/64) = exp2(f * -log2(10000)/64)
    constexpr float NEG_LOG2_THETA_OVER_64 = -0.20762050593045494f;
    float c0, s0, c1, s1;
    sincosf(mult * exp2f((float)f0       * NEG_LOG2_THETA_OVER_64), &s0, &c0);
    sincosf(mult * exp2f((float)(f0 + 1) * NEG_LOG2_THETA_OVER_64), &s1, &c1);

    // ---- Phase 2: compute + NT stores ----
    #pragma unroll
    for (int i = 0; i < SLABS_PER_THREAD; ++i) {
        const unsigned t = base + (unsigned)i * SLAB_F4;
        f32x4 r;
        r.x = fmaf(c0, qa[i].x, -s0 * qa[i].y);
        r.y = fmaf(s0, qa[i].x,  c0 * qa[i].y);
        r.z = fmaf(c1, qa[i].z, -s1 * qa[i].w);
        r.w = fmaf(s1, qa[i].z,  c1 * qa[i].w);
        __builtin_nontemporal_store(r, &oq4[t]);

        r.x = fmaf(c0, ka[i].x, -s0 * ka[i].y);
        r.y = fmaf(s0, ka[i].x,  c0 * ka[i].y);
        r.z = fmaf(c1, ka[i].z, -s1 * ka[i].w);
        r.w = fmaf(s1, ka[i].z,  c1 * ka[i].w);
        __builtin_nontemporal_store(r, &ok4[t]);
    }
}

extern "C" void kernel_launch(void* const* d_in, const int* in_sizes, int n_in,
                              void* d_out, int out_size, void* d_ws, size_t ws_size,
                              hipStream_t stream) {
    // dict order: q, k, h, w  (h,w are 1-element arrays on device)
    const int* wp = (const int*)d_in[3];
    float* out = (float*)d_out;                 // q_out flat, then k_out flat

    rope2d_batch_kernel<<<dim3(NBLOCKS), 256, 0, stream>>>(
        (const f32x4*)d_in[0], (const f32x4*)d_in[1], wp,
        (f32x4*)out, (f32x4*)(out + TENS));
}